// Round 5
// baseline (773.448 us; speedup 1.0000x reference)
//
#include <hip/hip_runtime.h>
#include <hip/hip_bf16.h>

#define S_LEN 2048
#define BATCH 8
#define HID   1024
#define NP    3072      // permuted gate dim: i,g,o only (f is dead in reference)
#define MROWS 16384     // S*B

using bf16x8 = __attribute__((ext_vector_type(8))) short;
using f32x4  = __attribute__((ext_vector_type(4))) float;

__device__ __forceinline__ unsigned short f2b(float f) {
  unsigned int u = __builtin_bit_cast(unsigned int, f);
  u += 0x7fffu + ((u >> 16) & 1u);   // RNE
  return (unsigned short)(u >> 16);
}

__device__ __forceinline__ float sigf(float x) {
  return 1.f / (1.f + __expf(-x));
}
__device__ __forceinline__ float tanh_f(float x) {
  return 2.f / (1.f + __expf(-2.f * x)) - 1.f;   // exact limits at +-inf
}

__device__ __forceinline__ void load_lds16(const void* g, void* l) {
  __builtin_amdgcn_global_load_lds(
      (const __attribute__((address_space(1))) void*)g,
      (__attribute__((address_space(3))) void*)(unsigned int)(unsigned long long)l,
      16, 0, 0);
}

#define MEMFENCE asm volatile("" ::: "memory")
#define BARRIER  do { MEMFENCE; __builtin_amdgcn_s_barrier(); MEMFENCE; } while (0)
#define LGKM0    asm volatile("s_waitcnt lgkmcnt(0)" ::: "memory")
#define WAITV(NA, NB) do {                                            \
    if (wid < 4) asm volatile("s_waitcnt vmcnt(" #NA ")" ::: "memory"); \
    else         asm volatile("s_waitcnt vmcnt(" #NB ")" ::: "memory"); \
  } while (0)
#define NOOP ((void)0)

// ---- fp32 -> bf16 convert (vectorized float4 -> ushort4) ----
__global__ void cvt_f32_bf16(const float* __restrict__ in,
                             unsigned short* __restrict__ out, int n4) {
  int i = blockIdx.x * blockDim.x + threadIdx.x;
  if (i >= n4) return;
  const float4 v = reinterpret_cast<const float4*>(in)[i];
  ushort4 u;
  u.x = f2b(v.x); u.y = f2b(v.y); u.z = f2b(v.z); u.w = f2b(v.w);
  reinterpret_cast<ushort4*>(out)[i] = u;
}

// ---- weight permute+convert: Wp[n'][k], n' = chunk*48 + gate3*16 + hl ----
__global__ void permute_w(const float* __restrict__ W,
                          unsigned short* __restrict__ Wp, int K) {
  long i = ((long)blockIdx.x * blockDim.x + threadIdx.x) * 4;
  int np = (int)(i / K);
  if (np >= NP) return;
  int k0 = (int)(i % K);
  int chunk = np / 48, rem = np % 48;
  int g3 = rem >> 4, hl = rem & 15;
  int og = (g3 == 0) ? 0 : (g3 == 1) ? 2 : 3;
  int n  = og * 1024 + chunk * 16 + hl;
  const float4 v = *reinterpret_cast<const float4*>(W + (long)n * K + k0);
  ushort4 u;
  u.x = f2b(v.x); u.y = f2b(v.y); u.z = f2b(v.z); u.w = f2b(v.w);
  *reinterpret_cast<ushort4*>(Wp + i) = u;
}

__global__ void permute_b(const float* __restrict__ b, float* __restrict__ bp) {
  int np = blockIdx.x * blockDim.x + threadIdx.x;
  if (np >= NP) return;
  int chunk = np / 48, rem = np % 48;
  int g3 = rem >> 4, hl = rem & 15;
  int og = (g3 == 0) ? 0 : (g3 == 1) ? 2 : 3;
  bp[np] = b[og * 1024 + chunk * 16 + hl];
}

// ---- fused GEMM + gates, counted-vmcnt 4-phase pipeline.
//  C = A[M,K] * Wp[NP,K]^T. Block 256x192, BK=64, 512 thr (8 waves 4Mx2N),
//  wave tile 64x96 (4mf x 6nf), 48 MFMA/K-tile/wave.
//  LDS: 4 k-half buffers of 28KB: A[256r x 32k] (128 lines x 128B, row-pairs)
//  + B[192r x 32k] @16384. Buffer for (t,kh) = (2t+kh)&3. Depth-2 prefetch;
//  waves 0-3 stage A (Q=4 slices/half), waves 4-7 stage B (Q=3).
//  Steady-state waits vmcnt(3Q) -- never 0. ----
#define MFMAOP(a_, b_, c_) \
  c_ = __builtin_amdgcn_mfma_f32_16x16x32_bf16(a_, b_, c_, 0, 0, 0)

#define PH12(B0, B1, B2, N0, N1, N2) do {                     \
    __builtin_amdgcn_s_setprio(1);                            \
    MFMAOP(aa0, B0, acc[0][N0]); MFMAOP(aa1, B0, acc[1][N0]); \
    MFMAOP(aa2, B0, acc[2][N0]); MFMAOP(aa3, B0, acc[3][N0]); \
    MFMAOP(aa0, B1, acc[0][N1]); MFMAOP(aa1, B1, acc[1][N1]); \
    MFMAOP(aa2, B1, acc[2][N1]); MFMAOP(aa3, B1, acc[3][N1]); \
    MFMAOP(aa0, B2, acc[0][N2]); MFMAOP(aa1, B2, acc[1][N2]); \
    MFMAOP(aa2, B2, acc[2][N2]); MFMAOP(aa3, B2, acc[3][N2]); \
    __builtin_amdgcn_s_setprio(0);                            \
  } while (0)

template <int MODE>  // 0: layer0 (bf16 out), 1: layer1 (fp32 out to d_out)
__global__ void __launch_bounds__(512, 2)
lstm_gemm(const unsigned short* __restrict__ A,
          const unsigned short* __restrict__ WpF,
          const unsigned short* __restrict__ WpB,
          const float* __restrict__ bpF, const float* __restrict__ bpB,
          int K,
          unsigned short* __restrict__ out_bf, float* __restrict__ out_f,
          float* __restrict__ hn, float* __restrict__ cn) {
  __shared__ __align__(16) char lds[114688];   // 4 x 28672

  const int dir = blockIdx.z;
  const unsigned short* __restrict__ Wp = dir ? WpB : WpF;
  const float* __restrict__ bp = dir ? bpB : bpF;
  const int bm = blockIdx.y;   // 256-row band of A
  const int bn = blockIdx.x;   // 192-col band (4 h-chunks)

  const int tid  = threadIdx.x;
  const int wid  = tid >> 6;
  const int lane = tid & 63;
  const int wm   = wid >> 1;   // 0..3
  const int wn   = wid & 1;    // 0..1

  const int  nt = K >> 6;
  const long K2 = (long)K * 2;

  // ---- staging: per-lane swizzled global source, uniform linear LDS dest.
  //  LDS line L (128B) holds rows {2L, 2L+1}; logical slot s (16B): row 2L+(s>>2),
  //  k-bytes (s&3)*16 of the 64B k-half window; phys slot = s ^ (L&7).
  const char* src[4];
  int dst[4];
  {
    const int lline = lane >> 3;   // line within 8-line slice
    const int lphys = lane & 7;    // phys slot
    if (wid < 4) {
#pragma unroll
      for (int j = 0; j < 4; ++j) {
        const int line0 = (wid * 4 + j) * 8;      // A: 128 lines total
        const int line  = line0 + lline;
        const int s     = lphys ^ (line & 7);
        const long grow = (long)bm * 256 + line * 2 + (s >> 2);
        src[j] = (const char*)A + grow * K2 + (s & 3) * 16;
        dst[j] = line0 * 128;
      }
    } else {
      const int bw = wid - 4;
#pragma unroll
      for (int j = 0; j < 3; ++j) {
        const int line0 = (bw * 3 + j) * 8;       // B: 96 lines total
        const int line  = line0 + lline;
        const int s     = lphys ^ (line & 7);
        const long grow = (long)bn * 192 + line * 2 + (s >> 2);
        src[j] = (const char*)Wp + grow * K2 + (s & 3) * 16;
        dst[j] = 16384 + line0 * 128;
      }
      src[3] = nullptr; dst[3] = 0;
    }
  }

#define ISSUE(T, KH) do {                                        \
    char* ibuf_ = lds + ((2 * (T) + (KH)) & 3) * 28672;          \
    const long koff_ = (long)(T) * 128 + (KH) * 64;              \
    if (wid < 4) {                                               \
      _Pragma("unroll") for (int j_ = 0; j_ < 4; ++j_)           \
        load_lds16(src[j_] + koff_, ibuf_ + dst[j_]);            \
    } else {                                                     \
      _Pragma("unroll") for (int j_ = 0; j_ < 3; ++j_)           \
        load_lds16(src[j_] + koff_, ibuf_ + dst[j_]);            \
    }                                                            \
  } while (0)

  // ---- frag-read byte offsets (within a k-half buffer) ----
  const int l15 = lane & 15;
  const int hi  = lane >> 4;
  auto mkA = [&](int mf) {
    const int r = wm * 64 + mf * 16 + l15, ln = r >> 1;
    return ln * 128 + (((((r & 1) << 2) | hi) ^ (ln & 7)) * 16);
  };
  auto mkB = [&](int nf) {
    const int r = wn * 96 + nf * 16 + l15, ln = r >> 1;
    return 16384 + ln * 128 + (((((r & 1) << 2) | hi) ^ (ln & 7)) * 16);
  };
  const int aoff0 = mkA(0), aoff1 = mkA(1), aoff2 = mkA(2), aoff3 = mkA(3);
  const int boff0 = mkB(0), boff1 = mkB(1), boff2 = mkB(2);
  const int boff3 = mkB(3), boff4 = mkB(4), boff5 = mkB(5);

  f32x4 acc[4][6];
  const f32x4 zero = {0.f, 0.f, 0.f, 0.f};
#pragma unroll
  for (int i = 0; i < 4; ++i)
#pragma unroll
    for (int j = 0; j < 6; ++j) acc[i][j] = zero;

#define TILE_BODY(T, ISS1, ISS3, V1A, V1B, V3A, V3B) do {            \
    const char* bh0_ = lds + (((2 * (T))    ) & 3) * 28672;          \
    const char* bh1_ = lds + (((2 * (T)) + 1) & 3) * 28672;          \
    bf16x8 aa0, aa1, aa2, aa3, bb0, bb1, bb2;                        \
    /* PH1: issue (t+1,kh1); counted wait for (t,kh0); reads+MFMA */ \
    ISS1;                                                            \
    WAITV(V1A, V1B);                                                 \
    BARRIER;                                                         \
    aa0 = *(const bf16x8*)(bh0_ + aoff0);                            \
    aa1 = *(const bf16x8*)(bh0_ + aoff1);                            \
    aa2 = *(const bf16x8*)(bh0_ + aoff2);                            \
    aa3 = *(const bf16x8*)(bh0_ + aoff3);                            \
    bb0 = *(const bf16x8*)(bh0_ + boff0);                            \
    bb1 = *(const bf16x8*)(bh0_ + boff1);                            \
    bb2 = *(const bf16x8*)(bh0_ + boff2);                            \
    PH12(bb0, bb1, bb2, 0, 1, 2);                                    \
    /* PH2 */                                                        \
    bb0 = *(const bf16x8*)(bh0_ + boff3);                            \
    bb1 = *(const bf16x8*)(bh0_ + boff4);                            \
    bb2 = *(const bf16x8*)(bh0_ + boff5);                            \
    PH12(bb0, bb1, bb2, 3, 4, 5);                                    \
    LGKM0; BARRIER;   /* (t,kh0) reads done block-wide */            \
    /* PH3: issue (t+2,kh0) into freed buffer; wait (t,kh1) */       \
    ISS3;                                                            \
    WAITV(V3A, V3B);                                                 \
    BARRIER;                                                         \
    aa0 = *(const bf16x8*)(bh1_ + aoff0);                            \
    aa1 = *(const bf16x8*)(bh1_ + aoff1);                            \
    aa2 = *(const bf16x8*)(bh1_ + aoff2);                            \
    aa3 = *(const bf16x8*)(bh1_ + aoff3);                            \
    bb0 = *(const bf16x8*)(bh1_ + boff0);                            \
    bb1 = *(const bf16x8*)(bh1_ + boff1);                            \
    bb2 = *(const bf16x8*)(bh1_ + boff2);                            \
    PH12(bb0, bb1, bb2, 0, 1, 2);                                    \
    /* PH4 */                                                        \
    bb0 = *(const bf16x8*)(bh1_ + boff3);                            \
    bb1 = *(const bf16x8*)(bh1_ + boff4);                            \
    bb2 = *(const bf16x8*)(bh1_ + boff5);                            \
    PH12(bb0, bb1, bb2, 3, 4, 5);                                    \
    LGKM0; BARRIER;   /* (t,kh1) reads done block-wide */            \
  } while (0)

  // prologue: 3 half-tiles in flight (per-wave 3Q outstanding)
  ISSUE(0, 0); MEMFENCE;
  ISSUE(0, 1); MEMFENCE;
  ISSUE(1, 0); MEMFENCE;

#pragma unroll 1
  for (int t = 0; t < nt - 2; ++t) {
    TILE_BODY(t, ISSUE(t + 1, 1), ISSUE(t + 2, 0), 12, 9, 12, 9);
  }
  TILE_BODY(nt - 2, ISSUE(nt - 1, 1), NOOP, 12, 9, 8, 6);
  TILE_BODY(nt - 1, NOOP, NOOP, 4, 3, 0, 0);

#undef TILE_BODY
#undef ISSUE

  // ---- epilogue: gates -> h (and h_n/c_n rows) ----
  const int col    = l15;
  const int rbase  = hi * 4;
  const int chunk0 = bn * 4 + wn * 2;
  const int Lidx   = MODE * 2 + dir;

#pragma unroll
  for (int hg = 0; hg < 2; ++hg) {
    const int chunk  = chunk0 + hg;
    const int h      = chunk * 16 + col;
    const int outcol = dir * HID + h;
    const float bi = bp[chunk * 48 + col];
    const float bg = bp[chunk * 48 + 16 + col];
    const float bo = bp[chunk * 48 + 32 + col];
#pragma unroll
    for (int mf = 0; mf < 4; ++mf) {
#pragma unroll
      for (int r = 0; r < 4; ++r) {
        const int m = bm * 256 + wm * 64 + mf * 16 + rbase + r;
        const float iv = acc[mf][hg * 3 + 0][r] + bi;
        const float gv = acc[mf][hg * 3 + 1][r] + bg;
        const float ov = acc[mf][hg * 3 + 2][r] + bo;
        const float is = sigf(iv);
        const float gt = tanh_f(gv);
        const float os = sigf(ov);
        const float c  = is * gt;
        const float hv = os * tanh_f(c);
        if (MODE == 0) {
          out_bf[(long)m * 2048 + outcol] = f2b(hv);
        } else {
          out_f[(long)m * 2048 + outcol] = hv;
        }
        const bool wst = (dir == 0) ? (m >= (S_LEN - 1) * BATCH) : (m < BATCH);
        if (wst) {
          const int b = (dir == 0) ? (m - (S_LEN - 1) * BATCH) : m;
          hn[((long)Lidx * BATCH + b) * HID + h] = hv;
          cn[((long)Lidx * BATCH + b) * HID + h] = c;
        }
      }
    }
  }
}

extern "C" void kernel_launch(void* const* d_in, const int* in_sizes, int n_in,
                              void* d_out, int out_size, void* d_ws, size_t ws_size,
                              hipStream_t stream) {
  const float* x    = (const float*)d_in[0];
  const float* W_f0 = (const float*)d_in[1];
  const float* b_f0 = (const float*)d_in[2];
  const float* W_b0 = (const float*)d_in[3];
  const float* b_b0 = (const float*)d_in[4];
  const float* W_f1 = (const float*)d_in[5];
  const float* b_f1 = (const float*)d_in[6];
  const float* W_b1 = (const float*)d_in[7];
  const float* b_b1 = (const float*)d_in[8];

  float* out = (float*)d_out;
  float* hn  = out + (long)MROWS * 2048;
  float* cn  = hn + 4 * BATCH * HID;

  unsigned short* x_bf  = (unsigned short*)d_ws;
  unsigned short* out1  = x_bf + (long)MROWS * 1024;
  unsigned short* wp_f0 = out1 + (long)MROWS * 2048;
  unsigned short* wp_b0 = wp_f0 + (long)NP * 1024;
  unsigned short* wp_f1 = wp_b0 + (long)NP * 1024;
  unsigned short* wp_b1 = wp_f1 + (long)NP * 2048;
  float* bp_f0 = (float*)(wp_b1 + (long)NP * 2048);
  float* bp_b0 = bp_f0 + NP;
  float* bp_f1 = bp_b0 + NP;
  float* bp_b1 = bp_f1 + NP;

  cvt_f32_bf16<<<16384, 256, 0, stream>>>(x, x_bf, MROWS * 1024 / 4);
  permute_w<<<3072, 256, 0, stream>>>(W_f0, wp_f0, 1024);
  permute_w<<<3072, 256, 0, stream>>>(W_b0, wp_b0, 1024);
  permute_w<<<6144, 256, 0, stream>>>(W_f1, wp_f1, 2048);
  permute_w<<<6144, 256, 0, stream>>>(W_b1, wp_b1, 2048);
  permute_b<<<12, 256, 0, stream>>>(b_f0, bp_f0);
  permute_b<<<12, 256, 0, stream>>>(b_b0, bp_b0);
  permute_b<<<12, 256, 0, stream>>>(b_f1, bp_f1);
  permute_b<<<12, 256, 0, stream>>>(b_b1, bp_b1);

  dim3 grid(NP / 192, MROWS / 256, 2);
  lstm_gemm<0><<<grid, 512, 0, stream>>>(x_bf, wp_f0, wp_b0, bp_f0, bp_b0, 1024,
                                         out1, nullptr, hn, cn);
  lstm_gemm<1><<<grid, 512, 0, stream>>>(out1, wp_f1, wp_b1, bp_f1, bp_b1, 2048,
                                         nullptr, out, hn, cn);
}

// Round 6
// 739.515 us; speedup vs baseline: 1.0459x; 1.0459x over previous
//
#include <hip/hip_runtime.h>
#include <hip/hip_bf16.h>

#define S_LEN 2048
#define BATCH 8
#define HID   1024
#define NP    3072      // permuted gate dim: i,g,o only (f is dead in reference)
#define MROWS 16384     // S*B

using bf16x8 = __attribute__((ext_vector_type(8))) short;
using f32x16 = __attribute__((ext_vector_type(16))) float;

__device__ __forceinline__ unsigned short f2b(float f) {
  unsigned int u = __builtin_bit_cast(unsigned int, f);
  u += 0x7fffu + ((u >> 16) & 1u);   // RNE
  return (unsigned short)(u >> 16);
}

__device__ __forceinline__ float sigf(float x) {
  return 1.f / (1.f + __expf(-x));
}
__device__ __forceinline__ float tanh_f(float x) {
  return 2.f / (1.f + __expf(-2.f * x)) - 1.f;   // exact limits at +-inf
}

__device__ __forceinline__ void load_lds16(const void* g, void* l) {
  __builtin_amdgcn_global_load_lds(
      (const __attribute__((address_space(1))) void*)g,
      (__attribute__((address_space(3))) void*)(unsigned int)(unsigned long long)l,
      16, 0, 0);
}

#define MEMFENCE asm volatile("" ::: "memory")
#define BARRIER  do { MEMFENCE; __builtin_amdgcn_s_barrier(); MEMFENCE; } while (0)

// ---- fp32 -> bf16 convert (vectorized float4 -> ushort4) ----
__global__ void cvt_f32_bf16(const float* __restrict__ in,
                             unsigned short* __restrict__ out, int n4) {
  int i = blockIdx.x * blockDim.x + threadIdx.x;
  if (i >= n4) return;
  const float4 v = reinterpret_cast<const float4*>(in)[i];
  ushort4 u;
  u.x = f2b(v.x); u.y = f2b(v.y); u.z = f2b(v.z); u.w = f2b(v.w);
  reinterpret_cast<ushort4*>(out)[i] = u;
}

// ---- weight permute+convert: Wp[n'][k], n' = c32*96 + gate*32 + hl,
//      gate {0:i,1:g,2:o} -> orig rows {0,2,3}*1024 + c32*32 + hl ----
__global__ void permute_w(const float* __restrict__ W,
                          unsigned short* __restrict__ Wp, int K) {
  long i = ((long)blockIdx.x * blockDim.x + threadIdx.x) * 4;
  int np = (int)(i / K);
  if (np >= NP) return;
  int k0 = (int)(i % K);
  int c32 = np / 96, rem = np % 96;
  int gate = rem >> 5, hl = rem & 31;
  int og = (gate == 0) ? 0 : (gate == 1) ? 2 : 3;
  int n  = og * 1024 + c32 * 32 + hl;
  const float4 v = *reinterpret_cast<const float4*>(W + (long)n * K + k0);
  ushort4 u;
  u.x = f2b(v.x); u.y = f2b(v.y); u.z = f2b(v.z); u.w = f2b(v.w);
  *reinterpret_cast<ushort4*>(Wp + i) = u;
}

__global__ void permute_b(const float* __restrict__ b, float* __restrict__ bp) {
  int np = blockIdx.x * blockDim.x + threadIdx.x;
  if (np >= NP) return;
  int c32 = np / 96, rem = np % 96;
  int gate = rem >> 5, hl = rem & 31;
  int og = (gate == 0) ? 0 : (gate == 1) ? 2 : 3;
  bp[np] = b[og * 1024 + c32 * 32 + hl];
}

// ---- fused GEMM + gates, 32x32x16 MFMA, triple-buffered counted-vmcnt.
//  C = A[M,K] * Wp[NP,K]^T. Block 256x384, BK=32, 512 thr (8 waves 2Mx4N),
//  wave tile 128x96 = 4 mf(32) x 3 nf(32) = one 32-h group x {i,g,o}.
//  LDS: 3 buffers x 40960 B. Buffer layout: 128-B lines = row-pairs x 64 B,
//  8 slots/line XOR-swizzled by line&7 (bank-uniform for both gload-linear
//  writes and frag reads). A = lines 0..127 (@0), B = lines 0..191 (@16384).
//  Per tile: 5 gload_lds/wave (uniform), 14 ds_read_b128, 24 MFMA, 1 barrier.
//  Depth-2 prefetch; steady wait vmcnt(5) = loads issued 2 tiles ago. ----
#define MFMAOP(a_, b_, c_) \
  c_ = __builtin_amdgcn_mfma_f32_32x32x16_bf16(a_, b_, c_, 0, 0, 0)

template <int MODE>  // 0: layer0 (bf16 out), 1: layer1 (fp32 out to d_out)
__global__ void __launch_bounds__(512, 2)
lstm_gemm(const unsigned short* __restrict__ A,
          const unsigned short* __restrict__ WpF,
          const unsigned short* __restrict__ WpB,
          const float* __restrict__ bpF, const float* __restrict__ bpB,
          int K,
          unsigned short* __restrict__ out_bf, float* __restrict__ out_f,
          float* __restrict__ hn, float* __restrict__ cn) {
  __shared__ __align__(16) char lds[122880];   // 3 x 40960

  const int dir = blockIdx.z;
  const unsigned short* __restrict__ Wp = dir ? WpB : WpF;
  const float* __restrict__ bp = dir ? bpB : bpF;
  const int bm = blockIdx.y;   // 256-row band of A
  const int bn = blockIdx.x;   // 384-col band (4 gate-groups of 96)

  const int tid  = threadIdx.x;
  const int wid  = tid >> 6;   // 0..7
  const int lane = tid & 63;
  const int wm   = wid >> 2;   // 0..1
  const int wn   = wid & 3;    // 0..3

  const int  nt = K >> 5;      // BK=32
  const long K2 = (long)K * 2;

  // ---- staging slices: 40 slices of 1 KB (8 lines); wave w owns w+8j.
  //  LDS(line, phys p) = global(row 2*line+(lg>>2), 16B-chunk lg&3), lg=p^(line&7).
  const int lls = lane >> 3;   // line within slice
  const int phs = lane & 7;    // phys slot
  const char *s0, *s1, *s2, *s3, *s4;
  int d0, d1, d2, d3, d4;
#define MKSLICE(j, SRC, DD) do {                                   \
    const int sl = wid + 8 * (j);                                  \
    if (sl < 16) {  /* A slice */                                  \
      const int line = sl * 8 + lls;                               \
      const int lg   = phs ^ (line & 7);                           \
      const long grow = (long)bm * 256 + line * 2 + (lg >> 2);     \
      SRC = (const char*)A + grow * K2 + (lg & 3) * 16;            \
      DD  = sl * 1024;                                             \
    } else {        /* B slice */                                  \
      const int jb = sl - 16;                                      \
      const int line = jb * 8 + lls;                               \
      const int lg   = phs ^ (line & 7);                           \
      const long grow = (long)bn * 384 + line * 2 + (lg >> 2);     \
      SRC = (const char*)Wp + grow * K2 + (lg & 3) * 16;           \
      DD  = 16384 + jb * 1024;                                     \
    }                                                              \
  } while (0)
  MKSLICE(0, s0, d0); MKSLICE(1, s1, d1); MKSLICE(2, s2, d2);
  MKSLICE(3, s3, d3); MKSLICE(4, s4, d4);
#undef MKSLICE

#define ISSUE(T, DB) do {                                          \
    const long ko_ = (long)(T) * 64;                               \
    load_lds16(s0 + ko_, (DB) + d0);                               \
    load_lds16(s1 + ko_, (DB) + d1);                               \
    load_lds16(s2 + ko_, (DB) + d2);                               \
    load_lds16(s3 + ko_, (DB) + d3);                               \
    load_lds16(s4 + ko_, (DB) + d4);                               \
  } while (0)

  // ---- frag read offsets (s=0; s=1 is ^32). row -> line*128 + phys*16 ----
  const int l31 = lane & 31;
  const int b5  = lane >> 5;   // 0/1
  auto frag_off = [&](int row) {
    const int line = row >> 1;
    const int lg   = (row & 1) * 4 + b5;   // s=0
    return line * 128 + ((lg ^ (line & 7)) * 16);
  };
  const int a0o = frag_off(wm * 128 + 0  + l31);
  const int a1o = frag_off(wm * 128 + 32 + l31);
  const int a2o = frag_off(wm * 128 + 64 + l31);
  const int a3o = frag_off(wm * 128 + 96 + l31);
  const int b0o = 16384 + frag_off(wn * 96 + 0  + l31);
  const int b1o = 16384 + frag_off(wn * 96 + 32 + l31);
  const int b2o = 16384 + frag_off(wn * 96 + 64 + l31);

  f32x16 acc[4][3];
#pragma unroll
  for (int i = 0; i < 4; ++i)
#pragma unroll
    for (int j = 0; j < 3; ++j)
      acc[i][j] = (f32x16)(0.f);

  char* p0 = lds;
  char* p1 = lds + 40960;
  char* p2 = lds + 81920;

  // prologue: tiles 0,1 in flight; wait tile 0 (5 of 10 outstanding retire)
  ISSUE(0, p0); MEMFENCE;
  ISSUE(1, p1); MEMFENCE;
  asm volatile("s_waitcnt vmcnt(5)" ::: "memory");
  BARRIER;

#define KSTEP(X) do {                                              \
    bf16x8 A0 = *(const bf16x8*)(p0 + (a0o ^ (X)));                \
    bf16x8 A1 = *(const bf16x8*)(p0 + (a1o ^ (X)));                \
    bf16x8 A2 = *(const bf16x8*)(p0 + (a2o ^ (X)));                \
    bf16x8 A3 = *(const bf16x8*)(p0 + (a3o ^ (X)));                \
    bf16x8 B0 = *(const bf16x8*)(p0 + (b0o ^ (X)));                \
    bf16x8 B1 = *(const bf16x8*)(p0 + (b1o ^ (X)));                \
    bf16x8 B2 = *(const bf16x8*)(p0 + (b2o ^ (X)));                \
    __builtin_amdgcn_s_setprio(1);                                 \
    MFMAOP(A0, B0, acc[0][0]); MFMAOP(A1, B0, acc[1][0]);          \
    MFMAOP(A2, B0, acc[2][0]); MFMAOP(A3, B0, acc[3][0]);          \
    MFMAOP(A0, B1, acc[0][1]); MFMAOP(A1, B1, acc[1][1]);          \
    MFMAOP(A2, B1, acc[2][1]); MFMAOP(A3, B1, acc[3][1]);          \
    MFMAOP(A0, B2, acc[0][2]); MFMAOP(A1, B2, acc[1][2]);          \
    MFMAOP(A2, B2, acc[2][2]); MFMAOP(A3, B2, acc[3][2]);          \
    __builtin_amdgcn_s_setprio(0);                                 \
  } while (0)

#pragma unroll 1
  for (int t = 0; t < nt; ++t) {
    if (t + 2 < nt) { ISSUE(t + 2, p2); }
    MEMFENCE;
    KSTEP(0);
    KSTEP(32);
    if (t < nt - 2) { asm volatile("s_waitcnt vmcnt(5)" ::: "memory"); }
    else            { asm volatile("s_waitcnt vmcnt(0)" ::: "memory"); }
    BARRIER;
    char* tp = p0; p0 = p1; p1 = p2; p2 = tp;   // rotate buffers
  }
#undef KSTEP
#undef ISSUE

  // ---- epilogue: gates -> h (and h_n/c_n rows).
  //  C layout (32x32): col = lane&31, row = (r&3) + 8*(r>>2) + 4*(lane>>5).
  const int c32  = bn * 4 + wn;          // 32-wide h-chunk
  const int h    = c32 * 32 + l31;
  const int outcol = dir * HID + h;
  const float bi = bp[c32 * 96 + l31];
  const float bg = bp[c32 * 96 + 32 + l31];
  const float bo = bp[c32 * 96 + 64 + l31];
  const int Lidx = MODE * 2 + dir;
  const int mrow0 = bm * 256 + wm * 128 + b5 * 4;

#pragma unroll
  for (int mf = 0; mf < 4; ++mf) {
#pragma unroll
    for (int r = 0; r < 16; ++r) {
      const int m = mrow0 + mf * 32 + (r & 3) + 8 * (r >> 2);
      const float iv = acc[mf][0][r] + bi;
      const float gv = acc[mf][1][r] + bg;
      const float ov = acc[mf][2][r] + bo;
      const float is = sigf(iv);
      const float gt = tanh_f(gv);
      const float os = sigf(ov);
      const float c  = is * gt;
      const float hv = os * tanh_f(c);
      if (MODE == 0) {
        out_bf[(long)m * 2048 + outcol] = f2b(hv);
      } else {
        out_f[(long)m * 2048 + outcol] = hv;
      }
      const bool wst = (dir == 0) ? (m >= (S_LEN - 1) * BATCH) : (m < BATCH);
      if (wst) {
        const int b = (dir == 0) ? (m - (S_LEN - 1) * BATCH) : m;
        hn[((long)Lidx * BATCH + b) * HID + h] = hv;
        cn[((long)Lidx * BATCH + b) * HID + h] = c;
      }
    }
  }
}

extern "C" void kernel_launch(void* const* d_in, const int* in_sizes, int n_in,
                              void* d_out, int out_size, void* d_ws, size_t ws_size,
                              hipStream_t stream) {
  const float* x    = (const float*)d_in[0];
  const float* W_f0 = (const float*)d_in[1];
  const float* b_f0 = (const float*)d_in[2];
  const float* W_b0 = (const float*)d_in[3];
  const float* b_b0 = (const float*)d_in[4];
  const float* W_f1 = (const float*)d_in[5];
  const float* b_f1 = (const float*)d_in[6];
  const float* W_b1 = (const float*)d_in[7];
  const float* b_b1 = (const float*)d_in[8];

  float* out = (float*)d_out;
  float* hn  = out + (long)MROWS * 2048;
  float* cn  = hn + 4 * BATCH * HID;

  unsigned short* x_bf  = (unsigned short*)d_ws;
  unsigned short* out1  = x_bf + (long)MROWS * 1024;
  unsigned short* wp_f0 = out1 + (long)MROWS * 2048;
  unsigned short* wp_b0 = wp_f0 + (long)NP * 1024;
  unsigned short* wp_f1 = wp_b0 + (long)NP * 1024;
  unsigned short* wp_b1 = wp_f1 + (long)NP * 2048;
  float* bp_f0 = (float*)(wp_b1 + (long)NP * 2048);
  float* bp_b0 = bp_f0 + NP;
  float* bp_f1 = bp_b0 + NP;
  float* bp_b1 = bp_f1 + NP;

  cvt_f32_bf16<<<16384, 256, 0, stream>>>(x, x_bf, MROWS * 1024 / 4);
  permute_w<<<3072, 256, 0, stream>>>(W_f0, wp_f0, 1024);
  permute_w<<<3072, 256, 0, stream>>>(W_b0, wp_b0, 1024);
  permute_w<<<6144, 256, 0, stream>>>(W_f1, wp_f1, 2048);
  permute_w<<<6144, 256, 0, stream>>>(W_b1, wp_b1, 2048);
  permute_b<<<12, 256, 0, stream>>>(b_f0, bp_f0);
  permute_b<<<12, 256, 0, stream>>>(b_b0, bp_b0);
  permute_b<<<12, 256, 0, stream>>>(b_f1, bp_f1);
  permute_b<<<12, 256, 0, stream>>>(b_b1, bp_b1);

  dim3 grid(NP / 384, MROWS / 256, 2);
  lstm_gemm<0><<<grid, 512, 0, stream>>>(x_bf, wp_f0, wp_b0, bp_f0, bp_b0, 1024,
                                         out1, nullptr, hn, cn);
  lstm_gemm<1><<<grid, 512, 0, stream>>>(out1, wp_f1, wp_b1, bp_f1, bp_b1, 2048,
                                         nullptr, out, hn, cn);
}

// Round 7
// 687.803 us; speedup vs baseline: 1.1245x; 1.0752x over previous
//
#include <hip/hip_runtime.h>
#include <hip/hip_bf16.h>

#define S_LEN 2048
#define BATCH 8
#define HID   1024
#define NP    3072      // permuted gate dim: i,g,o only (f is dead in reference)
#define MROWS 16384     // S*B

using bf16x8 = __attribute__((ext_vector_type(8))) short;
using f32x16 = __attribute__((ext_vector_type(16))) float;

__device__ __forceinline__ unsigned short f2b(float f) {
  unsigned int u = __builtin_bit_cast(unsigned int, f);
  u += 0x7fffu + ((u >> 16) & 1u);   // RNE
  return (unsigned short)(u >> 16);
}

__device__ __forceinline__ float sigf(float x) {
  return 1.f / (1.f + __expf(-x));
}
__device__ __forceinline__ float tanh_f(float x) {
  return 2.f / (1.f + __expf(-2.f * x)) - 1.f;   // exact limits at +-inf
}

__device__ __forceinline__ void load_lds16(const void* g, void* l) {
  __builtin_amdgcn_global_load_lds(
      (const __attribute__((address_space(1))) void*)g,
      (__attribute__((address_space(3))) void*)(unsigned int)(unsigned long long)l,
      16, 0, 0);
}

#define MEMFENCE asm volatile("" ::: "memory")
#define BARRIER  do { MEMFENCE; __builtin_amdgcn_s_barrier(); MEMFENCE; } while (0)

// ---- weight fragment-pack (device helper).
//  Wp flat 16B-chunk id = ((bn*nt + t)*24 + (nf*2 + ks))*64 + l
//  lane l holds: W row = og*1024 + (bn*4 + nf/3)*32 + (l&31)   (og={0,2,3}[nf%3])
//                k    = t*32 + ks*16 + (l>>5)*8 .. +8
__device__ __forceinline__ void pack_w_dev(const float* __restrict__ W,
                                           unsigned short* __restrict__ Wp,
                                           int id, int Kshift, int ntshift) {
  const int l = id & 63;
  const int q = id >> 6;
  const int c = q % 24;
  const int q24 = q / 24;
  const int t  = q24 & ((1 << ntshift) - 1);
  const int bn = q24 >> ntshift;
  const int nf = c >> 1, ks = c & 1;
  const int gate = nf % 3, hgrp = nf / 3;
  const int og = (gate == 0) ? 0 : (gate == 1) ? 2 : 3;
  const int row = og * 1024 + (bn * 4 + hgrp) * 32 + (l & 31);
  const int k   = t * 32 + ks * 16 + (l >> 5) * 8;
  const float* s = W + ((long)row << Kshift) + k;
  const float4 v0 = *reinterpret_cast<const float4*>(s);
  const float4 v1 = *reinterpret_cast<const float4*>(s + 4);
  uint4 o;
  o.x = (unsigned)f2b(v0.x) | ((unsigned)f2b(v0.y) << 16);
  o.y = (unsigned)f2b(v0.z) | ((unsigned)f2b(v0.w) << 16);
  o.z = (unsigned)f2b(v1.x) | ((unsigned)f2b(v1.y) << 16);
  o.w = (unsigned)f2b(v1.z) | ((unsigned)f2b(v1.w) << 16);
  *reinterpret_cast<uint4*>(Wp + (long)id * 8) = o;
}

// ---- single fused prep kernel: x cvt + 4 weight packs + 4 bias packs ----
__global__ void prep(const float* __restrict__ x, unsigned short* __restrict__ x_bf,
                     const float* __restrict__ Wf0, const float* __restrict__ Wb0,
                     const float* __restrict__ Wf1, const float* __restrict__ Wb1,
                     unsigned short* __restrict__ pf0, unsigned short* __restrict__ pb0,
                     unsigned short* __restrict__ pf1, unsigned short* __restrict__ pb1,
                     const float* __restrict__ bf0, const float* __restrict__ bb0,
                     const float* __restrict__ bf1, const float* __restrict__ bb1,
                     float* __restrict__ bpf0, float* __restrict__ bpb0,
                     float* __restrict__ bpf1, float* __restrict__ bpb1) {
  const int blk = blockIdx.x;
  const int tid = threadIdx.x;
  if (blk < 16384) {               // x: fp32 -> bf16, float4/thread (exact)
    const int i = blk * 256 + tid;
    const float4 v = reinterpret_cast<const float4*>(x)[i];
    ushort4 u;
    u.x = f2b(v.x); u.y = f2b(v.y); u.z = f2b(v.z); u.w = f2b(v.w);
    reinterpret_cast<ushort4*>(x_bf)[i] = u;
  } else if (blk < 17920) {
    pack_w_dev(Wf0, pf0, (blk - 16384) * 256 + tid, 10, 5);
  } else if (blk < 19456) {
    pack_w_dev(Wb0, pb0, (blk - 17920) * 256 + tid, 10, 5);
  } else if (blk < 22528) {
    pack_w_dev(Wf1, pf1, (blk - 19456) * 256 + tid, 11, 6);
  } else if (blk < 25600) {
    pack_w_dev(Wb1, pb1, (blk - 22528) * 256 + tid, 11, 6);
  } else {                         // biases: np = c32*96 + gate*32 + hl
    const int r = blk - 25600;     // 0..47
    const int which = r / 12;
    const int np = (r % 12) * 256 + tid;
    const float* bs = which == 0 ? bf0 : which == 1 ? bb0 : which == 2 ? bf1 : bb1;
    float* bd       = which == 0 ? bpf0 : which == 1 ? bpb0 : which == 2 ? bpf1 : bpb1;
    const int c32 = np / 96, rem = np % 96;
    const int gate = rem >> 5, hl = rem & 31;
    const int og = (gate == 0) ? 0 : (gate == 1) ? 2 : 3;
    bd[np] = bs[og * 1024 + c32 * 32 + hl];
  }
}

// ---- fused GEMM + gates. Fragment-linear LDS (zero-conflict by construction).
//  C = A[M,K] * W^T via fragment chunks. Block 256x384, BK=32, 512 thr
//  (8 waves 2Mx4N), wave tile 128x96 = 4mf x 3nf of 32x32x16 -> 24 MFMA/tile.
//  LDS: 2 buffers x 40KB. Buffer = 16 A-chunks (1KB each: lane i's 16B at
//  i*16) + 24 B-chunks @16384. A-chunk (f,ks): lane l = A[bm*256+f*32+(l&31)]
//  [t*32+ks*16+(l>>5)*8 ..+8]. B pre-packed in exactly this order.
//  Per tile: 5 gload_lds/wave, 14 linear ds_read_b128, 24 MFMA, 1 barrier. ----
#define MFMAOP(a_, b_, c_) \
  c_ = __builtin_amdgcn_mfma_f32_32x32x16_bf16(a_, b_, c_, 0, 0, 0)

template <int MODE>  // 0: layer0 (bf16 out), 1: layer1 (fp32 out to d_out)
__global__ void __launch_bounds__(512, 2)
lstm_gemm(const unsigned short* __restrict__ A,
          const unsigned short* __restrict__ PF,
          const unsigned short* __restrict__ PB,
          const float* __restrict__ bpF, const float* __restrict__ bpB,
          int K,
          unsigned short* __restrict__ out_bf, float* __restrict__ out_f,
          float* __restrict__ hn, float* __restrict__ cn) {
  __shared__ __align__(16) char lds[81920];   // 2 x 40960

  const int dir = blockIdx.z;
  const unsigned short* __restrict__ Wp = dir ? PB : PF;
  const float* __restrict__ bp = dir ? bpB : bpF;
  const int bm = blockIdx.y;   // 256-row band of A
  const int bn = blockIdx.x;   // 384-col band (4 h-chunks x {i,g,o})

  const int tid  = threadIdx.x;
  const int wid  = tid >> 6;   // 0..7
  const int lane = tid & 63;
  const int wm   = wid >> 2;   // 0..1
  const int wn   = wid & 3;    // 0..3
  const int l31  = lane & 31;
  const int b5   = lane >> 5;

  const int  nt = K >> 5;      // BK=32
  const long K2 = (long)K * 2;

  // ---- staging: wave stages chunks {wid, wid+8} (A) and {wid, wid+8, wid+16} (B)
  const char *srcA0, *srcA1;
  int dA0, dA1;
  {
    const int c0 = wid, c1 = wid + 8;
    srcA0 = (const char*)A + ((long)(bm * 256 + (c0 >> 1) * 32 + l31)) * K2
            + (c0 & 1) * 32 + b5 * 16;
    srcA1 = (const char*)A + ((long)(bm * 256 + (c1 >> 1) * 32 + l31)) * K2
            + (c1 & 1) * 32 + b5 * 16;
    dA0 = c0 * 1024; dA1 = c1 * 1024;
  }
  const char* srcB = (const char*)Wp + (long)bn * nt * 24576 + wid * 1024 + lane * 16;
  const int dB0 = 16384 + wid * 1024;

#define ISSUE(T) do {                                              \
    char* d_ = lds + ((T) & 1) * 40960;                            \
    const long ta_ = (long)(T) * 64;                               \
    const long tb_ = (long)(T) * 24576;                            \
    load_lds16(srcA0 + ta_, d_ + dA0);                             \
    load_lds16(srcA1 + ta_, d_ + dA1);                             \
    load_lds16(srcB + tb_,         d_ + dB0);                      \
    load_lds16(srcB + tb_ + 8192,  d_ + dB0 + 8192);               \
    load_lds16(srcB + tb_ + 16384, d_ + dB0 + 16384);              \
  } while (0)

  // ---- compute-side chunk bases (linear: + lane*16) ----
  const int abase = wm * 8192 + lane * 16;           // + mf*2048 + s*1024
  const int bbase = 16384 + wn * 6144 + lane * 16;   // + g*2048 + s*1024

  f32x16 acc[4][3];
#pragma unroll
  for (int i = 0; i < 4; ++i)
#pragma unroll
    for (int j = 0; j < 3; ++j)
      acc[i][j] = (f32x16)(0.f);

#define KSTEP(BUF, S) do {                                         \
    bf16x8 A0 = *(const bf16x8*)((BUF) + abase +        (S)*1024); \
    bf16x8 A1 = *(const bf16x8*)((BUF) + abase + 2048 + (S)*1024); \
    bf16x8 A2 = *(const bf16x8*)((BUF) + abase + 4096 + (S)*1024); \
    bf16x8 A3 = *(const bf16x8*)((BUF) + abase + 6144 + (S)*1024); \
    bf16x8 B0 = *(const bf16x8*)((BUF) + bbase +        (S)*1024); \
    bf16x8 B1 = *(const bf16x8*)((BUF) + bbase + 2048 + (S)*1024); \
    bf16x8 B2 = *(const bf16x8*)((BUF) + bbase + 4096 + (S)*1024); \
    __builtin_amdgcn_s_setprio(1);                                 \
    MFMAOP(A0, B0, acc[0][0]); MFMAOP(A1, B0, acc[1][0]);          \
    MFMAOP(A2, B0, acc[2][0]); MFMAOP(A3, B0, acc[3][0]);          \
    MFMAOP(A0, B1, acc[0][1]); MFMAOP(A1, B1, acc[1][1]);          \
    MFMAOP(A2, B1, acc[2][1]); MFMAOP(A3, B1, acc[3][1]);          \
    MFMAOP(A0, B2, acc[0][2]); MFMAOP(A1, B2, acc[1][2]);          \
    MFMAOP(A2, B2, acc[2][2]); MFMAOP(A3, B2, acc[3][2]);          \
    __builtin_amdgcn_s_setprio(0);                                 \
  } while (0)

  ISSUE(0);
  asm volatile("s_waitcnt vmcnt(0)" ::: "memory");
  BARRIER;

#pragma unroll 1
  for (int t = 0; t < nt; ++t) {
    if (t + 1 < nt) { ISSUE(t + 1); }   // latency hidden under reads + MFMA
    const char* buf = lds + (t & 1) * 40960;
    KSTEP(buf, 0);
    KSTEP(buf, 1);
    asm volatile("s_waitcnt vmcnt(0)" ::: "memory");
    BARRIER;
  }
#undef KSTEP
#undef ISSUE

  // ---- epilogue: gates -> h (and h_n/c_n rows).
  //  C layout (32x32): col = lane&31, row = (r&3) + 8*(r>>2) + 4*(lane>>5).
  const int c32  = bn * 4 + wn;          // 32-wide h-chunk
  const int h    = c32 * 32 + l31;
  const int outcol = dir * HID + h;
  const float bi = bp[c32 * 96 + l31];
  const float bg = bp[c32 * 96 + 32 + l31];
  const float bo = bp[c32 * 96 + 64 + l31];
  const int Lidx = MODE * 2 + dir;
  const int mrow0 = bm * 256 + wm * 128 + b5 * 4;

#pragma unroll
  for (int mf = 0; mf < 4; ++mf) {
#pragma unroll
    for (int r = 0; r < 16; ++r) {
      const int m = mrow0 + mf * 32 + (r & 3) + 8 * (r >> 2);
      const float iv = acc[mf][0][r] + bi;
      const float gv = acc[mf][1][r] + bg;
      const float ov = acc[mf][2][r] + bo;
      const float is = sigf(iv);
      const float gt = tanh_f(gv);
      const float os = sigf(ov);
      const float c  = is * gt;
      const float hv = os * tanh_f(c);
      if (MODE == 0) {
        out_bf[(long)m * 2048 + outcol] = f2b(hv);
      } else {
        out_f[(long)m * 2048 + outcol] = hv;
      }
      const bool wst = (dir == 0) ? (m >= (S_LEN - 1) * BATCH) : (m < BATCH);
      if (wst) {
        const int b = (dir == 0) ? (m - (S_LEN - 1) * BATCH) : m;
        hn[((long)Lidx * BATCH + b) * HID + h] = hv;
        cn[((long)Lidx * BATCH + b) * HID + h] = c;
      }
    }
  }
}

extern "C" void kernel_launch(void* const* d_in, const int* in_sizes, int n_in,
                              void* d_out, int out_size, void* d_ws, size_t ws_size,
                              hipStream_t stream) {
  const float* x    = (const float*)d_in[0];
  const float* W_f0 = (const float*)d_in[1];
  const float* b_f0 = (const float*)d_in[2];
  const float* W_b0 = (const float*)d_in[3];
  const float* b_b0 = (const float*)d_in[4];
  const float* W_f1 = (const float*)d_in[5];
  const float* b_f1 = (const float*)d_in[6];
  const float* W_b1 = (const float*)d_in[7];
  const float* b_b1 = (const float*)d_in[8];

  float* out = (float*)d_out;
  float* hn  = out + (long)MROWS * 2048;
  float* cn  = hn + 4 * BATCH * HID;

  unsigned short* x_bf  = (unsigned short*)d_ws;
  unsigned short* out1  = x_bf + (long)MROWS * 1024;
  unsigned short* wp_f0 = out1 + (long)MROWS * 2048;
  unsigned short* wp_b0 = wp_f0 + (long)NP * 1024;
  unsigned short* wp_f1 = wp_b0 + (long)NP * 1024;
  unsigned short* wp_b1 = wp_f1 + (long)NP * 2048;
  float* bp_f0 = (float*)(wp_b1 + (long)NP * 2048);
  float* bp_b0 = bp_f0 + NP;
  float* bp_f1 = bp_b0 + NP;
  float* bp_b1 = bp_f1 + NP;

  prep<<<25648, 256, 0, stream>>>(x, x_bf, W_f0, W_b0, W_f1, W_b1,
                                  wp_f0, wp_b0, wp_f1, wp_b1,
                                  b_f0, b_b0, b_f1, b_b1,
                                  bp_f0, bp_b0, bp_f1, bp_b1);

  dim3 grid(NP / 384, MROWS / 256, 2);
  lstm_gemm<0><<<grid, 512, 0, stream>>>(x_bf, wp_f0, wp_b0, bp_f0, bp_b0, 1024,
                                         out1, nullptr, hn, cn);
  lstm_gemm<1><<<grid, 512, 0, stream>>>(out1, wp_f1, wp_b1, bp_f1, bp_b1, 2048,
                                         nullptr, out, hn, cn);
}